// Round 1
// baseline (4290.807 us; speedup 1.0000x reference)
//
#include <hip/hip_runtime.h>
#include <hip/hip_bf16.h>

#define NVOX 200000
#define DIM 96
#define KVOL 343
#define NEDGE 3200000
#define HID 384
#define TM 64

typedef __attribute__((ext_vector_type(8))) __bf16 bf16x8;
typedef __attribute__((ext_vector_type(4))) float f32x4;

// ---------------- K1: x[i][c] = b_dw[c] ----------------
__global__ void init_x(const float* __restrict__ b_dw, float* __restrict__ x) {
    int tid = blockIdx.x * 256 + threadIdx.x;   // NVOX*DIM/4 threads
    int base = tid * 4;
    int c = base % DIM;
    float4 b = *(const float4*)(b_dw + c);
    *(float4*)(x + base) = b;
}

// ---------------- K2: scatter-accumulate ----------------
// thread = (edge, quad-of-channels); 24 threads per edge
__global__ void scatter(const float* __restrict__ feats, const float* __restrict__ w_dw,
                        const int* __restrict__ in_idx, const int* __restrict__ out_idx,
                        const int* __restrict__ k_idx, float* __restrict__ x) {
    unsigned tid = blockIdx.x * 256u + threadIdx.x;   // NEDGE*24 exactly
    unsigned e = tid / 24u;
    int q = (int)(tid % 24u) * 4;
    int i = in_idx[e], o = out_idx[e], k = k_idx[e];
    float4 f = *(const float4*)(feats + i * DIM + q);
    float4 w = *(const float4*)(w_dw + k * DIM + q);
    float* dst = x + o * DIM + q;
    atomicAdd(dst + 0, f.x * w.x);
    atomicAdd(dst + 1, f.y * w.y);
    atomicAdd(dst + 2, f.z * w.z);
    atomicAdd(dst + 3, f.w * w.w);
}

// ---------------- K3: weights -> bf16, transposed ----------------
// w1 [96][384] -> w1t [384][96]; w2 [384][96] -> w2t [96][384]
__global__ void conv_weights(const float* __restrict__ w1, const float* __restrict__ w2,
                             __hip_bfloat16* __restrict__ w1t, __hip_bfloat16* __restrict__ w2t) {
    int t = blockIdx.x * 256 + threadIdx.x;   // 36864 threads exactly
    int n1 = t / DIM, k1 = t % DIM;
    w1t[t] = __float2bfloat16(w1[k1 * HID + n1]);
    int n2 = t / HID, k2 = t % HID;
    w2t[t] = __float2bfloat16(w2[k2 * DIM + n2]);
}

// ---------------- K4: fused LN + MLP + residual ----------------
__global__ __launch_bounds__(256) void fused_ln_mlp(
    const float* __restrict__ x, const float* __restrict__ feats,
    const float* __restrict__ ln_w, const float* __restrict__ ln_b,
    const __hip_bfloat16* __restrict__ w1t, const float* __restrict__ b1,
    const __hip_bfloat16* __restrict__ w2t, const float* __restrict__ b2,
    float* __restrict__ out)
{
    __shared__ __hip_bfloat16 At[TM][104];   // 13,312 B (stride 104 breaks conflicts)
    __shared__ __hip_bfloat16 Ht[TM][392];   // 50,176 B

    const int t   = threadIdx.x;
    const int blk = blockIdx.x;

    // ---- LayerNorm phase: 4 threads per row (wave-local rows) ----
    {
        int row  = t >> 2;        // 0..63
        int part = t & 3;         // 0..3
        int g = blk * TM + row;   // 3125*64 == 200000 exactly, no tail
        const float* xr = x + g * DIM + part * 24;

        float v[24];
        float s = 0.f, s2 = 0.f;
        #pragma unroll
        for (int j = 0; j < 6; ++j) {
            float4 f = *(const float4*)(xr + j * 4);
            v[j*4+0] = f.x; v[j*4+1] = f.y; v[j*4+2] = f.z; v[j*4+3] = f.w;
            s  += f.x + f.y + f.z + f.w;
            s2 += f.x*f.x + f.y*f.y + f.z*f.z + f.w*f.w;
        }
        s  += __shfl_xor(s, 1);  s  += __shfl_xor(s, 2);
        s2 += __shfl_xor(s2, 1); s2 += __shfl_xor(s2, 2);
        float mean = s * (1.f / 96.f);
        float var  = s2 * (1.f / 96.f) - mean * mean;
        float rstd = rsqrtf(var + 1e-6f);

        int c0 = part * 24;
        float lw[24], lb[24];
        #pragma unroll
        for (int j = 0; j < 6; ++j) {
            *(float4*)&lw[j*4] = *(const float4*)(ln_w + c0 + j*4);
            *(float4*)&lb[j*4] = *(const float4*)(ln_b + c0 + j*4);
        }
        #pragma unroll
        for (int jj = 0; jj < 3; ++jj) {
            bf16x8 pack;
            #pragma unroll
            for (int j = 0; j < 8; ++j) {
                float xn = (v[jj*8+j] - mean) * rstd * lw[jj*8+j] + lb[jj*8+j];
                pack[j] = (__bf16)xn;
            }
            *(bf16x8*)&At[row][c0 + jj*8] = pack;
        }
    }
    __syncthreads();

    const int w  = t >> 6;    // wave 0..3 -> m-block
    const int l  = t & 63;
    const int lr = l & 15;
    const int lk = l >> 4;

    // ---- GEMM1: [64,96] @ [96,384], wave w owns rows w*16..+15 ----
    f32x4 acc[24];
    #pragma unroll
    for (int j = 0; j < 24; ++j) acc[j] = (f32x4){0.f, 0.f, 0.f, 0.f};

    #pragma unroll
    for (int kk = 0; kk < 3; ++kk) {
        bf16x8 a = *(const bf16x8*)&At[w*16 + lr][kk*32 + lk*8];
        #pragma unroll
        for (int j = 0; j < 24; ++j) {
            bf16x8 b = *(const bf16x8*)&w1t[(j*16 + lr) * DIM + kk*32 + lk*8];
            acc[j] = __builtin_amdgcn_mfma_f32_16x16x32_bf16(a, b, acc[j], 0, 0, 0);
        }
    }

    // ---- bias + exact GELU -> Ht (bf16) ----
    #pragma unroll
    for (int j = 0; j < 24; ++j) {
        int col = j*16 + lr;
        float bb = b1[col];
        #pragma unroll
        for (int r = 0; r < 4; ++r) {
            float vv = acc[j][r] + bb;
            float ge = 0.5f * vv * (1.f + erff(vv * 0.70710678118f));
            Ht[w*16 + lk*4 + r][col] = __float2bfloat16(ge);
        }
    }
    __syncthreads();

    // ---- GEMM2: [64,384] @ [384,96] ----
    f32x4 acc2[6];
    #pragma unroll
    for (int j = 0; j < 6; ++j) acc2[j] = (f32x4){0.f, 0.f, 0.f, 0.f};

    #pragma unroll
    for (int kk = 0; kk < 12; ++kk) {
        bf16x8 a = *(const bf16x8*)&Ht[w*16 + lr][kk*32 + lk*8];
        #pragma unroll
        for (int j = 0; j < 6; ++j) {
            bf16x8 b = *(const bf16x8*)&w2t[(j*16 + lr) * HID + kk*32 + lk*8];
            acc2[j] = __builtin_amdgcn_mfma_f32_16x16x32_bf16(a, b, acc2[j], 0, 0, 0);
        }
    }

    // ---- epilogue: + b2 + residual, write f32 ----
    #pragma unroll
    for (int j = 0; j < 6; ++j) {
        int col = j*16 + lr;
        float bb = b2[col];
        #pragma unroll
        for (int r = 0; r < 4; ++r) {
            int grow = blk * TM + w*16 + lk*4 + r;
            int off = grow * DIM + col;
            out[off] = acc2[j][r] + bb + feats[off];
        }
    }
}

extern "C" void kernel_launch(void* const* d_in, const int* in_sizes, int n_in,
                              void* d_out, int out_size, void* d_ws, size_t ws_size,
                              hipStream_t stream) {
    const float* feats = (const float*)d_in[0];
    const float* w_dw  = (const float*)d_in[1];
    const float* b_dw  = (const float*)d_in[2];
    const float* ln_w  = (const float*)d_in[3];
    const float* ln_b  = (const float*)d_in[4];
    const float* w1    = (const float*)d_in[5];
    const float* b1    = (const float*)d_in[6];
    const float* w2    = (const float*)d_in[7];
    const float* b2    = (const float*)d_in[8];
    const int* in_idx  = (const int*)d_in[9];
    const int* out_idx = (const int*)d_in[10];
    const int* k_idx   = (const int*)d_in[11];
    float* out = (float*)d_out;

    char* ws = (char*)d_ws;
    float* x = (float*)ws;                                        // 76,800,000 B
    __hip_bfloat16* w1t = (__hip_bfloat16*)(ws + 76800000);       // 73,728 B
    __hip_bfloat16* w2t = (__hip_bfloat16*)(ws + 76800000 + 73728);

    init_x<<<(NVOX * DIM / 4) / 256, 256, 0, stream>>>(b_dw, x);
    conv_weights<<<(HID * DIM) / 256, 256, 0, stream>>>(w1, w2, w1t, w2t);
    scatter<<<(NEDGE * 24) / 256, 256, 0, stream>>>(feats, w_dw, in_idx, out_idx, k_idx, x);
    fused_ln_mlp<<<NVOX / TM, 256, 0, stream>>>(x, feats, ln_w, ln_b, w1t, b1, w2t, b2, out);
}

// Round 2
// 2346.663 us; speedup vs baseline: 1.8285x; 1.8285x over previous
//
#include <hip/hip_runtime.h>
#include <hip/hip_bf16.h>

#define NVOX 200000
#define DIM 96
#define KVOL 343
#define NEDGE 3200000
#define HID 384
#define TM 64

typedef __attribute__((ext_vector_type(8))) __bf16 bf16x8;
typedef __attribute__((ext_vector_type(4))) float f32x4;

// ---------------- sort build ----------------
__global__ void zero_cnt(int* __restrict__ cnt) {
    int i = blockIdx.x * 256 + threadIdx.x;
    if (i < NVOX) cnt[i] = 0;
}

__global__ void hist(const int* __restrict__ out_idx, int* __restrict__ cnt) {
    int e = blockIdx.x * 256 + threadIdx.x;   // NEDGE exact
    atomicAdd(&cnt[out_idx[e]], 1);
}

// block scans 4096 counts (256 thr x 16), writes per-item exclusive prefix + block sum
__global__ void scanA(const int* __restrict__ cnt, int* __restrict__ offs,
                      int* __restrict__ bsum) {
    __shared__ int sh[256];
    int t = threadIdx.x, blk = blockIdx.x;
    int base = blk * 4096 + t * 16;
    int loc[16];
    int s = 0;
    #pragma unroll
    for (int j = 0; j < 16; ++j) {
        int i = base + j;
        int c = (i < NVOX) ? cnt[i] : 0;
        loc[j] = s; s += c;
    }
    sh[t] = s;
    __syncthreads();
    #pragma unroll
    for (int off = 1; off < 256; off <<= 1) {
        int v = (t >= off) ? sh[t - off] : 0;
        __syncthreads();
        sh[t] += v;
        __syncthreads();
    }
    int excl = sh[t] - s;
    #pragma unroll
    for (int j = 0; j < 16; ++j) {
        int i = base + j;
        if (i < NVOX) offs[i] = excl + loc[j];
    }
    if (t == 255) bsum[blk] = sh[255];
}

__global__ void scanB(const int* __restrict__ bsum, int* __restrict__ boffs, int nb) {
    if (threadIdx.x == 0) {
        int s = 0;
        for (int i = 0; i < nb; ++i) { boffs[i] = s; s += bsum[i]; }
    }
}

__global__ void scanC(int* __restrict__ offs, const int* __restrict__ boffs,
                      int* __restrict__ run) {
    int i = blockIdx.x * 256 + threadIdx.x;
    if (i < NVOX) {
        int v = offs[i] + boffs[i >> 12];
        offs[i] = v;
        run[i] = v;
    }
    if (i == 0) offs[NVOX] = NEDGE;
}

__global__ void reorder(const int* __restrict__ in_idx, const int* __restrict__ out_idx,
                        const int* __restrict__ k_idx, int* __restrict__ run,
                        unsigned long long* __restrict__ sorted) {
    int e = blockIdx.x * 256 + threadIdx.x;   // NEDGE exact
    int o = out_idx[e];
    int dst = atomicAdd(&run[o], 1);
    unsigned long long rec = (unsigned long long)(unsigned)in_idx[e]
                           | ((unsigned long long)(unsigned)k_idx[e] << 18)
                           | ((unsigned long long)(unsigned)(o & 63) << 27);
    sorted[dst] = rec;
}

// ---------------- weights -> bf16, transposed ----------------
__global__ void conv_weights(const float* __restrict__ w1, const float* __restrict__ w2,
                             __hip_bfloat16* __restrict__ w1t, __hip_bfloat16* __restrict__ w2t) {
    int t = blockIdx.x * 256 + threadIdx.x;   // 36864 threads exactly
    int n1 = t / DIM, k1 = t % DIM;
    w1t[t] = __float2bfloat16(w1[k1 * HID + n1]);
    int n2 = t / HID, k2 = t % HID;
    w2t[t] = __float2bfloat16(w2[k2 * DIM + n2]);
}

// ---------------- fused gather + LN + MLP + residual ----------------
#define XSTRIDE 97

__global__ __launch_bounds__(256) void fused_all(
    const float* __restrict__ feats, const float* __restrict__ w_dw,
    const float* __restrict__ b_dw,
    const float* __restrict__ ln_w, const float* __restrict__ ln_b,
    const __hip_bfloat16* __restrict__ w1t, const float* __restrict__ b1,
    const __hip_bfloat16* __restrict__ w2t, const float* __restrict__ b2,
    const unsigned long long* __restrict__ sorted, const int* __restrict__ offs,
    float* __restrict__ out)
{
    __shared__ __hip_bfloat16 At[TM][104];        // 13,312 B
    __shared__ float ubuf[64 * 392 / 2];          // 50,176 B: xtile (64x97 f32) | Ht (64x392 bf16)
    float* xtile = ubuf;
    __hip_bfloat16 (*Ht)[392] = (__hip_bfloat16(*)[392])ubuf;

    const int t   = threadIdx.x;
    const int blk = blockIdx.x;

    // ---- zero x tile ----
    for (int i = t; i < TM * XSTRIDE; i += 256) xtile[i] = 0.f;
    __syncthreads();

    // ---- gather phase: edge-parallel LDS accumulation ----
    {
        int e0 = offs[blk * TM];
        int e1 = offs[blk * TM + TM];
        int slot = t / 24;          // 0..10
        int q    = t % 24;
        if (slot < 10) {
            for (int j = e0 + slot; j < e1; j += 10) {
                unsigned long long rec = sorted[j];
                int i  = (int)(rec & 0x3FFFF);
                int k  = (int)((rec >> 18) & 0x1FF);
                int ol = (int)((rec >> 27) & 63);
                float4 f = *(const float4*)(feats + i * DIM + q * 4);
                float4 w = *(const float4*)(w_dw + k * DIM + q * 4);
                float* d = xtile + ol * XSTRIDE + q * 4;
                atomicAdd(d + 0, f.x * w.x);
                atomicAdd(d + 1, f.y * w.y);
                atomicAdd(d + 2, f.z * w.z);
                atomicAdd(d + 3, f.w * w.w);
            }
        }
    }
    __syncthreads();

    // ---- LayerNorm phase: 4 threads per row ----
    {
        int row  = t >> 2;
        int part = t & 3;
        int c0   = part * 24;
        const float* xr = xtile + row * XSTRIDE + c0;

        float v[24];
        float s = 0.f, s2 = 0.f;
        #pragma unroll
        for (int j = 0; j < 24; ++j) {
            float x = xr[j] + b_dw[c0 + j];
            v[j] = x;
            s += x; s2 += x * x;
        }
        s  += __shfl_xor(s, 1);  s  += __shfl_xor(s, 2);
        s2 += __shfl_xor(s2, 1); s2 += __shfl_xor(s2, 2);
        float mean = s * (1.f / 96.f);
        float var  = s2 * (1.f / 96.f) - mean * mean;
        float rstd = rsqrtf(var + 1e-6f);

        float lw[24], lb[24];
        #pragma unroll
        for (int j = 0; j < 6; ++j) {
            *(float4*)&lw[j*4] = *(const float4*)(ln_w + c0 + j*4);
            *(float4*)&lb[j*4] = *(const float4*)(ln_b + c0 + j*4);
        }
        __syncthreads();   // all xtile reads done before At/Ht region writes proceed
        #pragma unroll
        for (int jj = 0; jj < 3; ++jj) {
            bf16x8 pack;
            #pragma unroll
            for (int j = 0; j < 8; ++j) {
                float xn = (v[jj*8+j] - mean) * rstd * lw[jj*8+j] + lb[jj*8+j];
                pack[j] = (__bf16)xn;
            }
            *(bf16x8*)&At[row][c0 + jj*8] = pack;
        }
    }
    __syncthreads();

    const int w  = t >> 6;
    const int l  = t & 63;
    const int lr = l & 15;
    const int lk = l >> 4;

    // ---- GEMM1: [64,96] @ [96,384] ----
    f32x4 acc[24];
    #pragma unroll
    for (int j = 0; j < 24; ++j) acc[j] = (f32x4){0.f, 0.f, 0.f, 0.f};

    #pragma unroll
    for (int kk = 0; kk < 3; ++kk) {
        bf16x8 a = *(const bf16x8*)&At[w*16 + lr][kk*32 + lk*8];
        #pragma unroll
        for (int j = 0; j < 24; ++j) {
            bf16x8 b = *(const bf16x8*)&w1t[(j*16 + lr) * DIM + kk*32 + lk*8];
            acc[j] = __builtin_amdgcn_mfma_f32_16x16x32_bf16(a, b, acc[j], 0, 0, 0);
        }
    }

    // ---- bias + exact GELU -> Ht ----
    #pragma unroll
    for (int j = 0; j < 24; ++j) {
        int col = j*16 + lr;
        float bb = b1[col];
        #pragma unroll
        for (int r = 0; r < 4; ++r) {
            float vv = acc[j][r] + bb;
            float ge = 0.5f * vv * (1.f + erff(vv * 0.70710678118f));
            Ht[w*16 + lk*4 + r][col] = __float2bfloat16(ge);
        }
    }
    __syncthreads();

    // ---- GEMM2: [64,384] @ [384,96] ----
    f32x4 acc2[6];
    #pragma unroll
    for (int j = 0; j < 6; ++j) acc2[j] = (f32x4){0.f, 0.f, 0.f, 0.f};

    #pragma unroll
    for (int kk = 0; kk < 12; ++kk) {
        bf16x8 a = *(const bf16x8*)&Ht[w*16 + lr][kk*32 + lk*8];
        #pragma unroll
        for (int j = 0; j < 6; ++j) {
            bf16x8 b = *(const bf16x8*)&w2t[(j*16 + lr) * HID + kk*32 + lk*8];
            acc2[j] = __builtin_amdgcn_mfma_f32_16x16x32_bf16(a, b, acc2[j], 0, 0, 0);
        }
    }

    // ---- epilogue: + b2 + residual ----
    #pragma unroll
    for (int j = 0; j < 6; ++j) {
        int col = j*16 + lr;
        float bb = b2[col];
        #pragma unroll
        for (int r = 0; r < 4; ++r) {
            int grow = blk * TM + w*16 + lk*4 + r;
            int off = grow * DIM + col;
            out[off] = acc2[j][r] + bb + feats[off];
        }
    }
}

extern "C" void kernel_launch(void* const* d_in, const int* in_sizes, int n_in,
                              void* d_out, int out_size, void* d_ws, size_t ws_size,
                              hipStream_t stream) {
    const float* feats = (const float*)d_in[0];
    const float* w_dw  = (const float*)d_in[1];
    const float* b_dw  = (const float*)d_in[2];
    const float* ln_w  = (const float*)d_in[3];
    const float* ln_b  = (const float*)d_in[4];
    const float* w1    = (const float*)d_in[5];
    const float* b1    = (const float*)d_in[6];
    const float* w2    = (const float*)d_in[7];
    const float* b2    = (const float*)d_in[8];
    const int* in_idx  = (const int*)d_in[9];
    const int* out_idx = (const int*)d_in[10];
    const int* k_idx   = (const int*)d_in[11];
    float* out = (float*)d_out;

    char* ws = (char*)d_ws;
    unsigned long long* sorted = (unsigned long long*)ws;          // 25,600,000 B
    int* cnt   = (int*)(ws + 25600000);                            //    800,000 B
    int* offs  = (int*)(ws + 26400000);                            //    800,064 B (NVOX+1)
    int* run   = (int*)(ws + 27200064);                            //    800,000 B
    int* bsum  = (int*)(ws + 28000064);                            //        256 B
    int* boffs = (int*)(ws + 28000320);                            //        256 B
    __hip_bfloat16* w1t = (__hip_bfloat16*)(ws + 28000576);        //     73,728 B
    __hip_bfloat16* w2t = (__hip_bfloat16*)(ws + 28074304);        //     73,728 B

    const int NB_SCAN = (NVOX + 4095) / 4096;   // 49

    zero_cnt<<<(NVOX + 255) / 256, 256, 0, stream>>>(cnt);
    hist<<<NEDGE / 256, 256, 0, stream>>>(out_idx, cnt);
    scanA<<<NB_SCAN, 256, 0, stream>>>(cnt, offs, bsum);
    scanB<<<1, 64, 0, stream>>>(bsum, boffs, NB_SCAN);
    scanC<<<(NVOX + 255) / 256, 256, 0, stream>>>(offs, boffs, run);
    reorder<<<NEDGE / 256, 256, 0, stream>>>(in_idx, out_idx, k_idx, run, sorted);
    conv_weights<<<(HID * DIM) / 256, 256, 0, stream>>>(w1, w2, w1t, w2t);
    fused_all<<<NVOX / TM, 256, 0, stream>>>(feats, w_dw, b_dw, ln_w, ln_b,
                                             w1t, b1, w2t, b2, sorted, offs, out);
}

// Round 3
// 765.880 us; speedup vs baseline: 5.6025x; 3.0640x over previous
//
#include <hip/hip_runtime.h>
#include <hip/hip_bf16.h>

#define NVOX 200000
#define DIM 96
#define KVOL 343
#define NEDGE 3200000
#define HID 384
#define TM 64

typedef __attribute__((ext_vector_type(8))) __bf16 bf16x8;
typedef __attribute__((ext_vector_type(4))) float f32x4;

// ---------------- sort build ----------------
__global__ void zero_cnt(int* __restrict__ cnt) {
    int i = blockIdx.x * 256 + threadIdx.x;
    if (i < NVOX) cnt[i] = 0;
}

__global__ void hist(const int* __restrict__ out_idx, int* __restrict__ cnt) {
    int e = blockIdx.x * 256 + threadIdx.x;   // NEDGE exact
    atomicAdd(&cnt[out_idx[e]], 1);
}

__global__ void scanA(const int* __restrict__ cnt, int* __restrict__ offs,
                      int* __restrict__ bsum) {
    __shared__ int sh[256];
    int t = threadIdx.x, blk = blockIdx.x;
    int base = blk * 4096 + t * 16;
    int loc[16];
    int s = 0;
    #pragma unroll
    for (int j = 0; j < 16; ++j) {
        int i = base + j;
        int c = (i < NVOX) ? cnt[i] : 0;
        loc[j] = s; s += c;
    }
    sh[t] = s;
    __syncthreads();
    #pragma unroll
    for (int off = 1; off < 256; off <<= 1) {
        int v = (t >= off) ? sh[t - off] : 0;
        __syncthreads();
        sh[t] += v;
        __syncthreads();
    }
    int excl = sh[t] - s;
    #pragma unroll
    for (int j = 0; j < 16; ++j) {
        int i = base + j;
        if (i < NVOX) offs[i] = excl + loc[j];
    }
    if (t == 255) bsum[blk] = sh[255];
}

__global__ void scanB(const int* __restrict__ bsum, int* __restrict__ boffs, int nb) {
    if (threadIdx.x == 0) {
        int s = 0;
        for (int i = 0; i < nb; ++i) { boffs[i] = s; s += bsum[i]; }
    }
}

__global__ void scanC(int* __restrict__ offs, const int* __restrict__ boffs,
                      int* __restrict__ run) {
    int i = blockIdx.x * 256 + threadIdx.x;
    if (i < NVOX) {
        int v = offs[i] + boffs[i >> 12];
        offs[i] = v;
        run[i] = v;
    }
    if (i == 0) offs[NVOX] = NEDGE;
}

__global__ void reorder(const int* __restrict__ in_idx, const int* __restrict__ out_idx,
                        const int* __restrict__ k_idx, int* __restrict__ run,
                        unsigned* __restrict__ sorted) {
    int e = blockIdx.x * 256 + threadIdx.x;   // NEDGE exact
    int o = out_idx[e];
    int dst = atomicAdd(&run[o], 1);
    sorted[dst] = (unsigned)in_idx[e] | ((unsigned)k_idx[e] << 18);
}

// ---------------- weights -> bf16, transposed ----------------
__global__ void conv_weights(const float* __restrict__ w1, const float* __restrict__ w2,
                             __hip_bfloat16* __restrict__ w1t, __hip_bfloat16* __restrict__ w2t) {
    int t = blockIdx.x * 256 + threadIdx.x;   // 36864 threads exactly
    int n1 = t / DIM, k1 = t % DIM;
    w1t[t] = __float2bfloat16(w1[k1 * HID + n1]);
    int n2 = t / HID, k2 = t % HID;
    w2t[t] = __float2bfloat16(w2[k2 * DIM + n2]);
}

// ---------------- fused register-gather + LN + MLP + residual ----------------
__global__ __launch_bounds__(256, 4) void fused_all(
    const float* __restrict__ feats, const float* __restrict__ w_dw,
    const float* __restrict__ b_dw,
    const float* __restrict__ ln_w, const float* __restrict__ ln_b,
    const __hip_bfloat16* __restrict__ w1t, const float* __restrict__ b1,
    const __hip_bfloat16* __restrict__ w2t, const float* __restrict__ b2,
    const unsigned* __restrict__ sorted, const int* __restrict__ offs,
    float* __restrict__ out)
{
    __shared__ __hip_bfloat16 At[TM][104];   // 13,312 B (2-way bank alias: free)
    __shared__ __hip_bfloat16 Ht[TM][200];   // 25,600 B (half of H: 192 cols + pad)

    const int t   = threadIdx.x;
    const int blk = blockIdx.x;

    // ---- gather phase: thread (row, part) accumulates 24 channels in regs ----
    {
        const int row  = t >> 2;
        const int part = t & 3;
        const int c0   = part * 24;
        const int v    = blk * TM + row;

        float xa[24];
        #pragma unroll
        for (int j = 0; j < 24; ++j) xa[j] = 0.f;

        const int e0 = offs[v];
        const int e1 = offs[v + 1];
        for (int e = e0; e < e1; ++e) {
            unsigned rec = sorted[e];
            int i = (int)(rec & 0x3FFFFu);
            int k = (int)(rec >> 18);
            const float* fr = feats + i * DIM + c0;
            const float* wr = w_dw + k * DIM + c0;
            #pragma unroll
            for (int jj = 0; jj < 6; ++jj) {
                float4 f = *(const float4*)(fr + jj * 4);
                float4 w = *(const float4*)(wr + jj * 4);
                xa[jj*4+0] += f.x * w.x;
                xa[jj*4+1] += f.y * w.y;
                xa[jj*4+2] += f.z * w.z;
                xa[jj*4+3] += f.w * w.w;
            }
        }

        // ---- + b_dw, LayerNorm (4-lane quad reduce) ----
        float s = 0.f, s2 = 0.f;
        #pragma unroll
        for (int j = 0; j < 24; ++j) {
            float x = xa[j] + b_dw[c0 + j];
            xa[j] = x;
            s += x; s2 += x * x;
        }
        s  += __shfl_xor(s, 1);  s  += __shfl_xor(s, 2);
        s2 += __shfl_xor(s2, 1); s2 += __shfl_xor(s2, 2);
        float mean = s * (1.f / 96.f);
        float var  = s2 * (1.f / 96.f) - mean * mean;
        float rstd = rsqrtf(var + 1e-6f);

        #pragma unroll
        for (int jj = 0; jj < 3; ++jj) {
            bf16x8 pack;
            #pragma unroll
            for (int j = 0; j < 8; ++j) {
                int c = c0 + jj*8 + j;
                float xn = (xa[jj*8+j] - mean) * rstd * ln_w[c] + ln_b[c];
                pack[j] = (__bf16)xn;
            }
            *(bf16x8*)&At[row][c0 + jj*8] = pack;
        }
    }
    __syncthreads();

    const int w  = t >> 6;
    const int l  = t & 63;
    const int lr = l & 15;
    const int lk = l >> 4;

    f32x4 acc2[6];
    #pragma unroll
    for (int j = 0; j < 6; ++j) acc2[j] = (f32x4){0.f, 0.f, 0.f, 0.f};

    #pragma unroll
    for (int h = 0; h < 2; ++h) {
        // ---- GEMM1 half: [64,96] @ [96,192] ----
        f32x4 acc[12];
        #pragma unroll
        for (int j = 0; j < 12; ++j) acc[j] = (f32x4){0.f, 0.f, 0.f, 0.f};

        #pragma unroll
        for (int kk = 0; kk < 3; ++kk) {
            bf16x8 a = *(const bf16x8*)&At[w*16 + lr][kk*32 + lk*8];
            #pragma unroll
            for (int j = 0; j < 12; ++j) {
                int col = h*192 + j*16 + lr;
                bf16x8 b = *(const bf16x8*)&w1t[col * DIM + kk*32 + lk*8];
                acc[j] = __builtin_amdgcn_mfma_f32_16x16x32_bf16(a, b, acc[j], 0, 0, 0);
            }
        }

        if (h == 1) __syncthreads();   // GEMM2 pass 0 finished reading Ht

        // ---- bias + exact GELU -> Ht half ----
        #pragma unroll
        for (int j = 0; j < 12; ++j) {
            int col = h*192 + j*16 + lr;
            float bb = b1[col];
            #pragma unroll
            for (int r = 0; r < 4; ++r) {
                float vv = acc[j][r] + bb;
                float ge = 0.5f * vv * (1.f + erff(vv * 0.70710678f));
                Ht[w*16 + lk*4 + r][j*16 + lr] = __float2bfloat16(ge);
            }
        }
        __syncthreads();

        // ---- GEMM2 partial: [64,192] @ [192,96] ----
        #pragma unroll
        for (int kk = 0; kk < 6; ++kk) {
            bf16x8 a = *(const bf16x8*)&Ht[w*16 + lr][kk*32 + lk*8];
            #pragma unroll
            for (int j = 0; j < 6; ++j) {
                bf16x8 b = *(const bf16x8*)&w2t[(j*16 + lr) * HID + (h*6 + kk)*32 + lk*8];
                acc2[j] = __builtin_amdgcn_mfma_f32_16x16x32_bf16(a, b, acc2[j], 0, 0, 0);
            }
        }
    }

    // ---- epilogue: + b2 + residual ----
    #pragma unroll
    for (int j = 0; j < 6; ++j) {
        int col = j*16 + lr;
        float bb = b2[col];
        #pragma unroll
        for (int r = 0; r < 4; ++r) {
            int grow = blk * TM + w*16 + lk*4 + r;
            int off = grow * DIM + col;
            out[off] = acc2[j][r] + bb + feats[off];
        }
    }
}

extern "C" void kernel_launch(void* const* d_in, const int* in_sizes, int n_in,
                              void* d_out, int out_size, void* d_ws, size_t ws_size,
                              hipStream_t stream) {
    const float* feats = (const float*)d_in[0];
    const float* w_dw  = (const float*)d_in[1];
    const float* b_dw  = (const float*)d_in[2];
    const float* ln_w  = (const float*)d_in[3];
    const float* ln_b  = (const float*)d_in[4];
    const float* w1    = (const float*)d_in[5];
    const float* b1    = (const float*)d_in[6];
    const float* w2    = (const float*)d_in[7];
    const float* b2    = (const float*)d_in[8];
    const int* in_idx  = (const int*)d_in[9];
    const int* out_idx = (const int*)d_in[10];
    const int* k_idx   = (const int*)d_in[11];
    float* out = (float*)d_out;

    char* ws = (char*)d_ws;
    unsigned* sorted = (unsigned*)ws;                              // 12,800,000 B
    int* cnt   = (int*)(ws + 12800000);                            //    800,000 B
    int* offs  = (int*)(ws + 13600000);                            //    800,064 B (NVOX+1)
    int* run   = (int*)(ws + 14400064);                            //    800,000 B
    int* bsum  = (int*)(ws + 15200064);                            //        256 B
    int* boffs = (int*)(ws + 15200320);                            //        256 B
    __hip_bfloat16* w1t = (__hip_bfloat16*)(ws + 15200576);        //     73,728 B
    __hip_bfloat16* w2t = (__hip_bfloat16*)(ws + 15274304);        //     73,728 B

    const int NB_SCAN = (NVOX + 4095) / 4096;   // 49

    zero_cnt<<<(NVOX + 255) / 256, 256, 0, stream>>>(cnt);
    hist<<<NEDGE / 256, 256, 0, stream>>>(out_idx, cnt);
    scanA<<<NB_SCAN, 256, 0, stream>>>(cnt, offs, bsum);
    scanB<<<1, 64, 0, stream>>>(bsum, boffs, NB_SCAN);
    scanC<<<(NVOX + 255) / 256, 256, 0, stream>>>(offs, boffs, run);
    reorder<<<NEDGE / 256, 256, 0, stream>>>(in_idx, out_idx, k_idx, run, sorted);
    conv_weights<<<(HID * DIM) / 256, 256, 0, stream>>>(w1, w2, w1t, w2t);
    fused_all<<<NVOX / TM, 256, 0, stream>>>(feats, w_dw, b_dw, ln_w, ln_b,
                                             w1t, b1, w2t, b2, sorted, offs, out);
}

// Round 4
// 676.004 us; speedup vs baseline: 6.3473x; 1.1330x over previous
//
#include <hip/hip_runtime.h>
#include <hip/hip_bf16.h>

#define NVOX 200000
#define DIM 96
#define KVOL 343
#define NEDGE 3200000
#define HID 384
#define TM 32

typedef __attribute__((ext_vector_type(8))) __bf16 bf16x8;
typedef __attribute__((ext_vector_type(4))) __bf16 bf16x4;
typedef __attribute__((ext_vector_type(4))) float f32x4;

// ---------------- sort build ----------------
__global__ void zero_cnt(int* __restrict__ cnt) {
    int i = blockIdx.x * 256 + threadIdx.x;
    if (i < NVOX) cnt[i] = 0;
}

__global__ void hist(const int4* __restrict__ out4, int* __restrict__ cnt) {
    int t = blockIdx.x * 256 + threadIdx.x;   // NEDGE/4 exact
    int4 o = out4[t];
    atomicAdd(&cnt[o.x], 1);
    atomicAdd(&cnt[o.y], 1);
    atomicAdd(&cnt[o.z], 1);
    atomicAdd(&cnt[o.w], 1);
}

__global__ void scanA(const int* __restrict__ cnt, int* __restrict__ offs,
                      int* __restrict__ bsum) {
    __shared__ int sh[256];
    int t = threadIdx.x, blk = blockIdx.x;
    int base = blk * 4096 + t * 16;
    int loc[16];
    int s = 0;
    #pragma unroll
    for (int j = 0; j < 16; ++j) {
        int i = base + j;
        int c = (i < NVOX) ? cnt[i] : 0;
        loc[j] = s; s += c;
    }
    sh[t] = s;
    __syncthreads();
    #pragma unroll
    for (int off = 1; off < 256; off <<= 1) {
        int v = (t >= off) ? sh[t - off] : 0;
        __syncthreads();
        sh[t] += v;
        __syncthreads();
    }
    int excl = sh[t] - s;
    #pragma unroll
    for (int j = 0; j < 16; ++j) {
        int i = base + j;
        if (i < NVOX) offs[i] = excl + loc[j];
    }
    if (t == 255) bsum[blk] = sh[255];
}

// single-wave shuffle scan over nb<=64 block sums
__global__ void scanB(const int* __restrict__ bsum, int* __restrict__ boffs, int nb) {
    int l = threadIdx.x;   // 64 threads
    int v = (l < nb) ? bsum[l] : 0;
    int s = v;
    #pragma unroll
    for (int off = 1; off < 64; off <<= 1) {
        int u = __shfl_up(s, off);
        if (l >= off) s += u;
    }
    if (l < nb) boffs[l] = s - v;
}

__global__ void scanC(int* __restrict__ offs, const int* __restrict__ boffs,
                      int* __restrict__ run) {
    int i = blockIdx.x * 256 + threadIdx.x;
    if (i < NVOX) {
        int v = offs[i] + boffs[i >> 12];
        offs[i] = v;
        run[i] = v;
    }
    if (i == 0) offs[NVOX] = NEDGE;
}

__global__ void reorder(const int4* __restrict__ in4, const int4* __restrict__ out4,
                        const int4* __restrict__ k4, int* __restrict__ run,
                        unsigned* __restrict__ sorted) {
    int t = blockIdx.x * 256 + threadIdx.x;   // NEDGE/4 exact
    int4 i = in4[t], o = out4[t], k = k4[t];
    int d;
    d = atomicAdd(&run[o.x], 1); sorted[d] = (unsigned)i.x | ((unsigned)k.x << 18);
    d = atomicAdd(&run[o.y], 1); sorted[d] = (unsigned)i.y | ((unsigned)k.y << 18);
    d = atomicAdd(&run[o.z], 1); sorted[d] = (unsigned)i.z | ((unsigned)k.z << 18);
    d = atomicAdd(&run[o.w], 1); sorted[d] = (unsigned)i.w | ((unsigned)k.w << 18);
}

// ---------------- weight/feat conversions ----------------
__global__ void conv_weights(const float* __restrict__ w1, const float* __restrict__ w2,
                             const float* __restrict__ w_dw,
                             __hip_bfloat16* __restrict__ w1t,
                             __hip_bfloat16* __restrict__ w2t,
                             __bf16* __restrict__ wdwb) {
    int t = blockIdx.x * 256 + threadIdx.x;   // 36864 threads exactly
    int n1 = t / DIM, k1 = t % DIM;
    w1t[t] = __float2bfloat16(w1[k1 * HID + n1]);
    int n2 = t / HID, k2 = t % HID;
    w2t[t] = __float2bfloat16(w2[k2 * DIM + n2]);
    if (t < KVOL * DIM) wdwb[t] = (__bf16)w_dw[t];
}

__global__ void conv_feats(const float* __restrict__ f, __bf16* __restrict__ fb) {
    int t = blockIdx.x * 256 + threadIdx.x;   // NVOX*DIM/4 = 4.8M exact
    float4 v = *(const float4*)(f + t * 4);
    bf16x4 o;
    o[0] = (__bf16)v.x; o[1] = (__bf16)v.y; o[2] = (__bf16)v.z; o[3] = (__bf16)v.w;
    *(bf16x4*)(fb + t * 4) = o;
}

// ---------------- fused register-gather + LN + MLP + residual ----------------
__global__ __launch_bounds__(256, 5) void fused_all(
    const __bf16* __restrict__ featsb, const __bf16* __restrict__ wdwb,
    const float* __restrict__ b_dw,
    const float* __restrict__ ln_w, const float* __restrict__ ln_b,
    const __hip_bfloat16* __restrict__ w1t, const float* __restrict__ b1,
    const __hip_bfloat16* __restrict__ w2t, const float* __restrict__ b2,
    const unsigned* __restrict__ sorted, const int* __restrict__ offs,
    const float* __restrict__ feats, float* __restrict__ out)
{
    __shared__ __hip_bfloat16 At[TM][104];   //  6,656 B
    __shared__ __hip_bfloat16 Ht[TM][392];   // 25,088 B

    const int t   = threadIdx.x;
    const int blk = blockIdx.x;

    // ---- gather: 8 threads/voxel = 4 channel-parts x 2 edge-halves ----
    {
        const int row  = t >> 3;        // 0..31
        const int sub  = t & 7;
        const int part = sub & 3;       // channel quarter
        const int half = sub >> 2;      // edge half
        const int c0   = part * 24;
        const int v    = blk * TM + row;

        float xa[24];
        #pragma unroll
        for (int j = 0; j < 24; ++j) xa[j] = 0.f;

        const __bf16* fbase = featsb + c0;
        const __bf16* wbase = wdwb + c0;

        const int e0 = offs[v];
        const int e1 = offs[v + 1];
        int e = e0 + half;

        // unrolled by 2 (this thread strides 2)
        for (; e + 2 < e1; e += 4) {
            unsigned r0 = sorted[e];
            unsigned r1 = sorted[e + 2];
            const __bf16* fr0 = fbase + (int)(r0 & 0x3FFFFu) * DIM;
            const __bf16* wr0 = wbase + (int)(r0 >> 18) * DIM;
            const __bf16* fr1 = fbase + (int)(r1 & 0x3FFFFu) * DIM;
            const __bf16* wr1 = wbase + (int)(r1 >> 18) * DIM;
            #pragma unroll
            for (int jj = 0; jj < 3; ++jj) {
                bf16x8 f0 = *(const bf16x8*)(fr0 + jj * 8);
                bf16x8 w0 = *(const bf16x8*)(wr0 + jj * 8);
                bf16x8 f1 = *(const bf16x8*)(fr1 + jj * 8);
                bf16x8 w1v = *(const bf16x8*)(wr1 + jj * 8);
                #pragma unroll
                for (int j = 0; j < 8; ++j) {
                    xa[jj*8+j] += (float)f0[j] * (float)w0[j];
                    xa[jj*8+j] += (float)f1[j] * (float)w1v[j];
                }
            }
        }
        if (e < e1) {
            unsigned r0 = sorted[e];
            const __bf16* fr0 = fbase + (int)(r0 & 0x3FFFFu) * DIM;
            const __bf16* wr0 = wbase + (int)(r0 >> 18) * DIM;
            #pragma unroll
            for (int jj = 0; jj < 3; ++jj) {
                bf16x8 f0 = *(const bf16x8*)(fr0 + jj * 8);
                bf16x8 w0 = *(const bf16x8*)(wr0 + jj * 8);
                #pragma unroll
                for (int j = 0; j < 8; ++j)
                    xa[jj*8+j] += (float)f0[j] * (float)w0[j];
            }
        }

        // combine edge-halves (lanes differing in bit 2)
        #pragma unroll
        for (int j = 0; j < 24; ++j) xa[j] += __shfl_xor(xa[j], 4);

        // + b_dw, LayerNorm stats across 4 parts
        float s = 0.f, s2 = 0.f;
        #pragma unroll
        for (int j = 0; j < 24; ++j) {
            float x = xa[j] + b_dw[c0 + j];
            xa[j] = x;
            s += x; s2 += x * x;
        }
        s  += __shfl_xor(s, 1);  s  += __shfl_xor(s, 2);
        s2 += __shfl_xor(s2, 1); s2 += __shfl_xor(s2, 2);
        float mean = s * (1.f / 96.f);
        float var  = s2 * (1.f / 96.f) - mean * mean;
        float rstd = rsqrtf(var + 1e-6f);

        if (half == 0) {
            #pragma unroll
            for (int jj = 0; jj < 3; ++jj) {
                bf16x8 pack;
                #pragma unroll
                for (int j = 0; j < 8; ++j) {
                    int c = c0 + jj*8 + j;
                    float xn = (xa[jj*8+j] - mean) * rstd * ln_w[c] + ln_b[c];
                    pack[j] = (__bf16)xn;
                }
                *(bf16x8*)&At[row][c0 + jj*8] = pack;
            }
        }
    }
    __syncthreads();

    const int w  = t >> 6;
    const int l  = t & 63;
    const int lr = l & 15;
    const int lk = l >> 4;
    const int rb = w >> 1;    // row-block: rows rb*16..+15
    const int jh = w & 1;     // col-half

    // ---- GEMM1: [32,96] @ [96,384]; wave (rb,jh) does 16 rows x 192 cols ----
    f32x4 acc[12];
    #pragma unroll
    for (int j = 0; j < 12; ++j) acc[j] = (f32x4){0.f, 0.f, 0.f, 0.f};

    #pragma unroll
    for (int kk = 0; kk < 3; ++kk) {
        bf16x8 a = *(const bf16x8*)&At[rb*16 + lr][kk*32 + lk*8];
        #pragma unroll
        for (int j = 0; j < 12; ++j) {
            int col = jh*192 + j*16 + lr;
            bf16x8 b = *(const bf16x8*)&w1t[col * DIM + kk*32 + lk*8];
            acc[j] = __builtin_amdgcn_mfma_f32_16x16x32_bf16(a, b, acc[j], 0, 0, 0);
        }
    }

    // ---- bias + exact GELU -> Ht ----
    #pragma unroll
    for (int j = 0; j < 12; ++j) {
        int col = jh*192 + j*16 + lr;
        float bb = b1[col];
        #pragma unroll
        for (int r = 0; r < 4; ++r) {
            float vv = acc[j][r] + bb;
            float ge = 0.5f * vv * (1.f + erff(vv * 0.70710678f));
            Ht[rb*16 + lk*4 + r][col] = __float2bfloat16(ge);
        }
    }
    __syncthreads();

    // ---- GEMM2: [32,384] @ [384,96]; wave (rb,jh) does 16 rows x 48 cols ----
    f32x4 acc2[3];
    #pragma unroll
    for (int j = 0; j < 3; ++j) acc2[j] = (f32x4){0.f, 0.f, 0.f, 0.f};

    #pragma unroll
    for (int kk = 0; kk < 12; ++kk) {
        bf16x8 a = *(const bf16x8*)&Ht[rb*16 + lr][kk*32 + lk*8];
        #pragma unroll
        for (int j = 0; j < 3; ++j) {
            int col = jh*48 + j*16 + lr;
            bf16x8 b = *(const bf16x8*)&w2t[col * HID + kk*32 + lk*8];
            acc2[j] = __builtin_amdgcn_mfma_f32_16x16x32_bf16(a, b, acc2[j], 0, 0, 0);
        }
    }

    // ---- epilogue: + b2 + residual ----
    #pragma unroll
    for (int j = 0; j < 3; ++j) {
        int col = jh*48 + j*16 + lr;
        float bb = b2[col];
        #pragma unroll
        for (int r = 0; r < 4; ++r) {
            int grow = blk * TM + rb*16 + lk*4 + r;
            int off = grow * DIM + col;
            out[off] = acc2[j][r] + bb + feats[off];
        }
    }
}

extern "C" void kernel_launch(void* const* d_in, const int* in_sizes, int n_in,
                              void* d_out, int out_size, void* d_ws, size_t ws_size,
                              hipStream_t stream) {
    const float* feats = (const float*)d_in[0];
    const float* w_dw  = (const float*)d_in[1];
    const float* b_dw  = (const float*)d_in[2];
    const float* ln_w  = (const float*)d_in[3];
    const float* ln_b  = (const float*)d_in[4];
    const float* w1    = (const float*)d_in[5];
    const float* b1    = (const float*)d_in[6];
    const float* w2    = (const float*)d_in[7];
    const float* b2    = (const float*)d_in[8];
    const int* in_idx  = (const int*)d_in[9];
    const int* out_idx = (const int*)d_in[10];
    const int* k_idx   = (const int*)d_in[11];
    float* out = (float*)d_out;

    char* ws = (char*)d_ws;
    unsigned* sorted = (unsigned*)ws;                              // 12,800,000
    int* cnt   = (int*)(ws + 12800000);                            //    800,000
    int* offs  = (int*)(ws + 13600000);                            //    800,064
    int* run   = (int*)(ws + 14400064);                            //    800,000
    int* bsum  = (int*)(ws + 15200064);                            //        256
    int* boffs = (int*)(ws + 15200320);                            //        256
    __hip_bfloat16* w1t = (__hip_bfloat16*)(ws + 15200576);        //     73,728
    __hip_bfloat16* w2t = (__hip_bfloat16*)(ws + 15274304);        //     73,728
    __bf16* wdwb = (__bf16*)(ws + 15348032);                       //     65,856
    __bf16* featsb = (__bf16*)(ws + 15413888);                     // 38,400,000

    const int NB_SCAN = (NVOX + 4095) / 4096;   // 49

    zero_cnt<<<(NVOX + 255) / 256, 256, 0, stream>>>(cnt);
    hist<<<NEDGE / 4 / 256, 256, 0, stream>>>((const int4*)out_idx, cnt);
    scanA<<<NB_SCAN, 256, 0, stream>>>(cnt, offs, bsum);
    scanB<<<1, 64, 0, stream>>>(bsum, boffs, NB_SCAN);
    scanC<<<(NVOX + 255) / 256, 256, 0, stream>>>(offs, boffs, run);
    reorder<<<NEDGE / 4 / 256, 256, 0, stream>>>((const int4*)in_idx, (const int4*)out_idx,
                                                 (const int4*)k_idx, run, sorted);
    conv_weights<<<(HID * DIM) / 256, 256, 0, stream>>>(w1, w2, w_dw, w1t, w2t, wdwb);
    conv_feats<<<(NVOX * DIM / 4) / 256, 256, 0, stream>>>(feats, featsb);
    fused_all<<<NVOX / TM, 256, 0, stream>>>(featsb, wdwb, b_dw, ln_w, ln_b,
                                             w1t, b1, w2t, b2, sorted, offs, feats, out);
}

// Round 5
// 588.640 us; speedup vs baseline: 7.2894x; 1.1484x over previous
//
#include <hip/hip_runtime.h>
#include <hip/hip_bf16.h>

#define NVOX 200000
#define DIM 96
#define KVOL 343
#define NEDGE 3200000
#define HID 384
#define TM 32
#define SLOT_CAP 64

typedef __attribute__((ext_vector_type(8))) __bf16 bf16x8;
typedef __attribute__((ext_vector_type(4))) __bf16 bf16x4;
typedef __attribute__((ext_vector_type(4))) float f32x4;

// ---------------- prep: feats->bf16, weights->bf16 transposed, zero cnt ----------------
__global__ void prep(const float* __restrict__ feats, const float* __restrict__ w1,
                     const float* __restrict__ w2, const float* __restrict__ w_dw,
                     __bf16* __restrict__ featsb, __hip_bfloat16* __restrict__ w1t,
                     __hip_bfloat16* __restrict__ w2t, __bf16* __restrict__ wdwb,
                     int* __restrict__ cnt) {
    int t = blockIdx.x * 256 + threadIdx.x;   // NVOX*DIM/4 = 4.8M exact
    float4 v = *(const float4*)(feats + t * 4);
    bf16x4 o;
    o[0] = (__bf16)v.x; o[1] = (__bf16)v.y; o[2] = (__bf16)v.z; o[3] = (__bf16)v.w;
    *(bf16x4*)(featsb + t * 4) = o;
    if (t < HID * DIM) {
        int n1 = t / DIM, k1 = t % DIM;
        w1t[t] = __float2bfloat16(w1[k1 * HID + n1]);
        int n2 = t / HID, k2 = t % HID;
        w2t[t] = __float2bfloat16(w2[k2 * DIM + n2]);
        if (t < KVOL * DIM) wdwb[t] = (__bf16)w_dw[t];
    }
    if (t < NVOX) cnt[t] = 0;
}

// ---------------- scatter edges into fixed-cap per-voxel slots ----------------
__global__ void scatter_slots(const int4* __restrict__ in4, const int4* __restrict__ out4,
                              const int4* __restrict__ k4, int* __restrict__ cnt,
                              unsigned* __restrict__ slots) {
    int t = blockIdx.x * 256 + threadIdx.x;   // NEDGE/4 exact
    int4 i = in4[t], o = out4[t], k = k4[t];
    int d;
    d = atomicAdd(&cnt[o.x], 1); slots[o.x * SLOT_CAP + d] = (unsigned)i.x | ((unsigned)k.x << 18);
    d = atomicAdd(&cnt[o.y], 1); slots[o.y * SLOT_CAP + d] = (unsigned)i.y | ((unsigned)k.y << 18);
    d = atomicAdd(&cnt[o.z], 1); slots[o.z * SLOT_CAP + d] = (unsigned)i.z | ((unsigned)k.z << 18);
    d = atomicAdd(&cnt[o.w], 1); slots[o.w * SLOT_CAP + d] = (unsigned)i.w | ((unsigned)k.w << 18);
}

// ---------------- fused register-gather + LN + MLP + residual ----------------
__global__ __launch_bounds__(256, 8) void fused_all(
    const __bf16* __restrict__ featsb, const __bf16* __restrict__ wdwb,
    const float* __restrict__ b_dw,
    const float* __restrict__ ln_w, const float* __restrict__ ln_b,
    const __hip_bfloat16* __restrict__ w1t, const float* __restrict__ b1,
    const __hip_bfloat16* __restrict__ w2t, const float* __restrict__ b2,
    const unsigned* __restrict__ slots, const int* __restrict__ cnt,
    float* __restrict__ out)
{
    __shared__ __hip_bfloat16 At[TM][104];   //  6,656 B
    __shared__ __hip_bfloat16 Ht[TM][200];   // 12,800 B (half of H: 192 cols + pad)

    const int t   = threadIdx.x;
    const int blk = blockIdx.x;

    // ---- gather: 8 threads/voxel = 4 channel-parts x 2 edge-halves ----
    {
        const int row  = t >> 3;        // 0..31
        const int sub  = t & 7;
        const int part = sub & 3;       // channel quarter
        const int half = sub >> 2;      // edge half
        const int c0   = part * 24;
        const int v    = blk * TM + row;

        float xa[24];
        #pragma unroll
        for (int j = 0; j < 24; ++j) xa[j] = 0.f;

        const __bf16* fbase = featsb + c0;
        const __bf16* wbase = wdwb + c0;

        const int c = cnt[v];
        const unsigned* sp = slots + v * SLOT_CAP;
        int e = half;

        for (; e + 2 < c; e += 4) {
            unsigned r0 = sp[e];
            unsigned r1 = sp[e + 2];
            const __bf16* fr0 = fbase + (int)(r0 & 0x3FFFFu) * DIM;
            const __bf16* wr0 = wbase + (int)(r0 >> 18) * DIM;
            const __bf16* fr1 = fbase + (int)(r1 & 0x3FFFFu) * DIM;
            const __bf16* wr1 = wbase + (int)(r1 >> 18) * DIM;
            #pragma unroll
            for (int jj = 0; jj < 3; ++jj) {
                bf16x8 f0 = *(const bf16x8*)(fr0 + jj * 8);
                bf16x8 w0 = *(const bf16x8*)(wr0 + jj * 8);
                bf16x8 f1 = *(const bf16x8*)(fr1 + jj * 8);
                bf16x8 w1v = *(const bf16x8*)(wr1 + jj * 8);
                #pragma unroll
                for (int j = 0; j < 8; ++j) {
                    xa[jj*8+j] += (float)f0[j] * (float)w0[j];
                    xa[jj*8+j] += (float)f1[j] * (float)w1v[j];
                }
            }
        }
        if (e < c) {
            unsigned r0 = sp[e];
            const __bf16* fr0 = fbase + (int)(r0 & 0x3FFFFu) * DIM;
            const __bf16* wr0 = wbase + (int)(r0 >> 18) * DIM;
            #pragma unroll
            for (int jj = 0; jj < 3; ++jj) {
                bf16x8 f0 = *(const bf16x8*)(fr0 + jj * 8);
                bf16x8 w0 = *(const bf16x8*)(wr0 + jj * 8);
                #pragma unroll
                for (int j = 0; j < 8; ++j)
                    xa[jj*8+j] += (float)f0[j] * (float)w0[j];
            }
        }

        // combine edge-halves (lanes differing in bit 2)
        #pragma unroll
        for (int j = 0; j < 24; ++j) xa[j] += __shfl_xor(xa[j], 4);

        // + b_dw, LayerNorm stats across 4 parts
        float s = 0.f, s2 = 0.f;
        #pragma unroll
        for (int j = 0; j < 24; ++j) {
            float x = xa[j] + b_dw[c0 + j];
            xa[j] = x;
            s += x; s2 += x * x;
        }
        s  += __shfl_xor(s, 1);  s  += __shfl_xor(s, 2);
        s2 += __shfl_xor(s2, 1); s2 += __shfl_xor(s2, 2);
        float mean = s * (1.f / 96.f);
        float var  = s2 * (1.f / 96.f) - mean * mean;
        float rstd = rsqrtf(var + 1e-6f);

        if (half == 0) {
            #pragma unroll
            for (int jj = 0; jj < 3; ++jj) {
                bf16x8 pack;
                #pragma unroll
                for (int j = 0; j < 8; ++j) {
                    int cch = c0 + jj*8 + j;
                    float xn = (xa[jj*8+j] - mean) * rstd * ln_w[cch] + ln_b[cch];
                    pack[j] = (__bf16)xn;
                }
                *(bf16x8*)&At[row][c0 + jj*8] = pack;
            }
        }
    }
    __syncthreads();

    const int w  = t >> 6;
    const int l  = t & 63;
    const int lr = l & 15;
    const int lk = l >> 4;
    const int rb = w >> 1;    // row-block: rows rb*16..+15
    const int jh = w & 1;     // col-half within the current 192-col slab

    f32x4 acc2[3];
    #pragma unroll
    for (int j = 0; j < 3; ++j) acc2[j] = (f32x4){0.f, 0.f, 0.f, 0.f};

    #pragma unroll
    for (int h = 0; h < 2; ++h) {
        // ---- GEMM1 half: [32,96] @ [96,192]; wave (rb,jh): 16 rows x 96 cols ----
        f32x4 acc[6];
        #pragma unroll
        for (int j = 0; j < 6; ++j) acc[j] = (f32x4){0.f, 0.f, 0.f, 0.f};

        #pragma unroll
        for (int kk = 0; kk < 3; ++kk) {
            bf16x8 a = *(const bf16x8*)&At[rb*16 + lr][kk*32 + lk*8];
            #pragma unroll
            for (int j = 0; j < 6; ++j) {
                int col = h*192 + jh*96 + j*16 + lr;
                bf16x8 b = *(const bf16x8*)&w1t[col * DIM + kk*32 + lk*8];
                acc[j] = __builtin_amdgcn_mfma_f32_16x16x32_bf16(a, b, acc[j], 0, 0, 0);
            }
        }

        if (h == 1) __syncthreads();   // GEMM2 pass 0 finished reading Ht

        // ---- bias + exact GELU -> Ht half ----
        #pragma unroll
        for (int j = 0; j < 6; ++j) {
            int col = h*192 + jh*96 + j*16 + lr;
            float bb = b1[col];
            #pragma unroll
            for (int r = 0; r < 4; ++r) {
                float vv = acc[j][r] + bb;
                float ge = 0.5f * vv * (1.f + erff(vv * 0.70710678f));
                Ht[rb*16 + lk*4 + r][jh*96 + j*16 + lr] = __float2bfloat16(ge);
            }
        }
        __syncthreads();

        // ---- GEMM2 partial: [32,192] @ [192,96]; wave (rb,jh): 16 rows x 48 cols ----
        #pragma unroll
        for (int kk = 0; kk < 6; ++kk) {
            bf16x8 a = *(const bf16x8*)&Ht[rb*16 + lr][kk*32 + lk*8];
            #pragma unroll
            for (int j = 0; j < 3; ++j) {
                int col = jh*48 + j*16 + lr;
                bf16x8 b = *(const bf16x8*)&w2t[col * HID + (h*6 + kk)*32 + lk*8];
                acc2[j] = __builtin_amdgcn_mfma_f32_16x16x32_bf16(a, b, acc2[j], 0, 0, 0);
            }
        }
    }

    // ---- epilogue: + b2 + residual (bf16 feats) ----
    #pragma unroll
    for (int j = 0; j < 3; ++j) {
        int col = jh*48 + j*16 + lr;
        float bb = b2[col];
        #pragma unroll
        for (int r = 0; r < 4; ++r) {
            int grow = blk * TM + rb*16 + lk*4 + r;
            int off = grow * DIM + col;
            out[off] = acc2[j][r] + bb + (float)featsb[off];
        }
    }
}

extern "C" void kernel_launch(void* const* d_in, const int* in_sizes, int n_in,
                              void* d_out, int out_size, void* d_ws, size_t ws_size,
                              hipStream_t stream) {
    const float* feats = (const float*)d_in[0];
    const float* w_dw  = (const float*)d_in[1];
    const float* b_dw  = (const float*)d_in[2];
    const float* ln_w  = (const float*)d_in[3];
    const float* ln_b  = (const float*)d_in[4];
    const float* w1    = (const float*)d_in[5];
    const float* b1    = (const float*)d_in[6];
    const float* w2    = (const float*)d_in[7];
    const float* b2    = (const float*)d_in[8];
    const int* in_idx  = (const int*)d_in[9];
    const int* out_idx = (const int*)d_in[10];
    const int* k_idx   = (const int*)d_in[11];
    float* out = (float*)d_out;

    char* ws = (char*)d_ws;
    unsigned* slots = (unsigned*)ws;                               // 51,200,000
    int* cnt   = (int*)(ws + 51200000);                            //    800,000
    __hip_bfloat16* w1t = (__hip_bfloat16*)(ws + 52000000);        //     73,728
    __hip_bfloat16* w2t = (__hip_bfloat16*)(ws + 52073728);        //     73,728
    __bf16* wdwb = (__bf16*)(ws + 52147456);                       //     65,856
    __bf16* featsb = (__bf16*)(ws + 52213312);                     // 38,400,000

    prep<<<(NVOX * DIM / 4) / 256, 256, 0, stream>>>(feats, w1, w2, w_dw,
                                                     featsb, w1t, w2t, wdwb, cnt);
    scatter_slots<<<NEDGE / 4 / 256, 256, 0, stream>>>((const int4*)in_idx,
                                                       (const int4*)out_idx,
                                                       (const int4*)k_idx, cnt, slots);
    fused_all<<<NVOX / TM, 256, 0, stream>>>(featsb, wdwb, b_dw, ln_w, ln_b,
                                             w1t, b1, w2t, b2, slots, cnt, out);
}

// Round 6
// 535.004 us; speedup vs baseline: 8.0201x; 1.1003x over previous
//
#include <hip/hip_runtime.h>
#include <hip/hip_bf16.h>

#define NVOX 200000
#define DIM 96
#define KVOL 343
#define NEDGE 3200000
#define HID 384
#define TM 32
#define SLOT_CAP 64

typedef __attribute__((ext_vector_type(8))) __bf16 bf16x8;
typedef __attribute__((ext_vector_type(4))) __bf16 bf16x4;
typedef __attribute__((ext_vector_type(4))) float f32x4;

// ---------------- prep: feats->bf16, weights->bf16 transposed, zero cnt ----------------
__global__ void prep(const float* __restrict__ feats, const float* __restrict__ w1,
                     const float* __restrict__ w2, const float* __restrict__ w_dw,
                     __bf16* __restrict__ featsb, __hip_bfloat16* __restrict__ w1t,
                     __hip_bfloat16* __restrict__ w2t, __bf16* __restrict__ wdwb,
                     int* __restrict__ cnt) {
    int t = blockIdx.x * 256 + threadIdx.x;   // NVOX*DIM/4 = 4.8M exact
    float4 v = *(const float4*)(feats + t * 4);
    bf16x4 o;
    o[0] = (__bf16)v.x; o[1] = (__bf16)v.y; o[2] = (__bf16)v.z; o[3] = (__bf16)v.w;
    *(bf16x4*)(featsb + t * 4) = o;
    if (t < HID * DIM) {
        int n1 = t / DIM, k1 = t % DIM;
        w1t[t] = __float2bfloat16(w1[k1 * HID + n1]);
        int n2 = t / HID, k2 = t % HID;
        w2t[t] = __float2bfloat16(w2[k2 * DIM + n2]);
        if (t < KVOL * DIM) wdwb[t] = (__bf16)w_dw[t];
    }
    if (t < NVOX) cnt[t] = 0;
}

// ---------------- scatter edges into fixed-cap per-voxel slots (NT stores) ----------------
__global__ void scatter_slots(const int4* __restrict__ in4, const int4* __restrict__ out4,
                              const int4* __restrict__ k4, int* __restrict__ cnt,
                              unsigned* __restrict__ slots) {
    int t = blockIdx.x * 256 + threadIdx.x;   // NEDGE/4 exact
    int4 i = in4[t], o = out4[t], k = k4[t];
    int d;
    d = atomicAdd(&cnt[o.x], 1);
    __builtin_nontemporal_store((unsigned)i.x | ((unsigned)k.x << 18), &slots[o.x * SLOT_CAP + d]);
    d = atomicAdd(&cnt[o.y], 1);
    __builtin_nontemporal_store((unsigned)i.y | ((unsigned)k.y << 18), &slots[o.y * SLOT_CAP + d]);
    d = atomicAdd(&cnt[o.z], 1);
    __builtin_nontemporal_store((unsigned)i.z | ((unsigned)k.z << 18), &slots[o.z * SLOT_CAP + d]);
    d = atomicAdd(&cnt[o.w], 1);
    __builtin_nontemporal_store((unsigned)i.w | ((unsigned)k.w << 18), &slots[o.w * SLOT_CAP + d]);
}

// ---------------- fused LDS-staged pipelined gather + LN + MLP + residual ----------------
__global__ __launch_bounds__(256, 4) void fused_all(
    const __bf16* __restrict__ featsb, const __bf16* __restrict__ wdwb,
    const float* __restrict__ b_dw,
    const float* __restrict__ ln_w, const float* __restrict__ ln_b,
    const __hip_bfloat16* __restrict__ w1t, const float* __restrict__ b1,
    const __hip_bfloat16* __restrict__ w2t, const float* __restrict__ b2,
    const unsigned* __restrict__ slots, const int* __restrict__ cnt,
    float* __restrict__ out)
{
    __shared__ __hip_bfloat16 At[TM][104];                 //  6,656 B
    __shared__ __align__(16) char shb[TM * 392 * 2];       // 25,088 B: recsL (gather) | Ht (MLP)
    __hip_bfloat16 (*Ht)[392] = (__hip_bfloat16 (*)[392])shb;
    unsigned (*recsL)[68] = (unsigned (*)[68])shb;         // 32 x 68 x 4 = 8,704 B (stride 68: bank-spread)

    const int t   = threadIdx.x;
    const int blk = blockIdx.x;

    // ---- gather: 8 threads/voxel = 4 channel-parts x 2 contiguous edge-halves ----
    {
        const int row  = t >> 3;        // 0..31
        const int sub  = t & 7;
        const int part = sub & 3;       // channel quarter
        const int half = sub >> 2;      // edge half
        const int c0   = part * 24;
        const int v    = blk * TM + row;

        int c = cnt[v];
        if (c > SLOT_CAP) c = SLOT_CAP;
        const unsigned* sp = slots + v * SLOT_CAP;

        // stage rec list into LDS (contiguous uint4 loads)
        if (sub * 4 < c)
            *(uint4*)&recsL[row][sub * 4] = *(const uint4*)(sp + sub * 4);
        if (32 + sub * 4 < c)
            *(uint4*)&recsL[row][32 + sub * 4] = *(const uint4*)(sp + 32 + sub * 4);
        __syncthreads();

        float xa[24];
        #pragma unroll
        for (int j = 0; j < 24; ++j) xa[j] = 0.f;

        const __bf16* fbase = featsb + c0;
        const __bf16* wbase = wdwb + c0;
        const unsigned* rl = recsL[row];

        const int e_lo = half ? (c >> 1) : 0;
        const int e_hi = half ? c : (c >> 1);

#define LDE(F, W, ee) { unsigned rr = rl[ee]; \
        const __bf16* fr = fbase + (int)(rr & 0x3FFFFu) * DIM; \
        const __bf16* wr = wbase + (int)(rr >> 18) * DIM; \
        F##0 = *(const bf16x8*)(fr);      W##0 = *(const bf16x8*)(wr); \
        F##1 = *(const bf16x8*)(fr + 8);  W##1 = *(const bf16x8*)(wr + 8); \
        F##2 = *(const bf16x8*)(fr + 16); W##2 = *(const bf16x8*)(wr + 16); }

#define ACC(F, W) { \
        _Pragma("unroll") for (int j = 0; j < 8; ++j) xa[j]      += (float)F##0[j] * (float)W##0[j]; \
        _Pragma("unroll") for (int j = 0; j < 8; ++j) xa[8 + j]  += (float)F##1[j] * (float)W##1[j]; \
        _Pragma("unroll") for (int j = 0; j < 8; ++j) xa[16 + j] += (float)F##2[j] * (float)W##2[j]; }

        bf16x8 Af0, Af1, Af2, Aw0, Aw1, Aw2, Bf0, Bf1, Bf2, Bw0, Bw1, Bw2;
        int e = e_lo;
        if (e + 2 <= e_hi) {
            LDE(Af, Aw, e); LDE(Bf, Bw, e + 1);
            e += 2;
            for (; e + 2 <= e_hi; e += 2) {
                bf16x8 Cf0, Cf1, Cf2, Cw0, Cw1, Cw2, Df0, Df1, Df2, Dw0, Dw1, Dw2;
                LDE(Cf, Cw, e); LDE(Df, Dw, e + 1);     // issue next pair
                ACC(Af, Aw); ACC(Bf, Bw);               // consume current pair
                Af0 = Cf0; Af1 = Cf1; Af2 = Cf2; Aw0 = Cw0; Aw1 = Cw1; Aw2 = Cw2;
                Bf0 = Df0; Bf1 = Df1; Bf2 = Df2; Bw0 = Dw0; Bw1 = Dw1; Bw2 = Dw2;
            }
            ACC(Af, Aw); ACC(Bf, Bw);
        }
        if (e < e_hi) {
            LDE(Af, Aw, e);
            ACC(Af, Aw);
        }
#undef LDE
#undef ACC

        // combine edge-halves (lanes differing in bit 2)
        #pragma unroll
        for (int j = 0; j < 24; ++j) xa[j] += __shfl_xor(xa[j], 4);

        // + b_dw, LayerNorm stats across 4 parts
        float s = 0.f, s2 = 0.f;
        #pragma unroll
        for (int j = 0; j < 24; ++j) {
            float x = xa[j] + b_dw[c0 + j];
            xa[j] = x;
            s += x; s2 += x * x;
        }
        s  += __shfl_xor(s, 1);  s  += __shfl_xor(s, 2);
        s2 += __shfl_xor(s2, 1); s2 += __shfl_xor(s2, 2);
        float mean = s * (1.f / 96.f);
        float var  = s2 * (1.f / 96.f) - mean * mean;
        float rstd = rsqrtf(var + 1e-6f);

        if (half == 0) {
            #pragma unroll
            for (int jj = 0; jj < 3; ++jj) {
                bf16x8 pack;
                #pragma unroll
                for (int j = 0; j < 8; ++j) {
                    int cch = c0 + jj*8 + j;
                    float xn = (xa[jj*8+j] - mean) * rstd * ln_w[cch] + ln_b[cch];
                    pack[j] = (__bf16)xn;
                }
                *(bf16x8*)&At[row][c0 + jj*8] = pack;
            }
        }
    }
    __syncthreads();   // At ready; all recsL reads done (Ht may now overwrite it)

    const int w  = t >> 6;
    const int l  = t & 63;
    const int lr = l & 15;
    const int lk = l >> 4;
    const int rb = w >> 1;    // row-block: rows rb*16..+15
    const int jh = w & 1;     // col-half

    // ---- GEMM1: [32,96] @ [96,384]; wave (rb,jh) does 16 rows x 192 cols ----
    f32x4 acc[12];
    #pragma unroll
    for (int j = 0; j < 12; ++j) acc[j] = (f32x4){0.f, 0.f, 0.f, 0.f};

    #pragma unroll
    for (int kk = 0; kk < 3; ++kk) {
        bf16x8 a = *(const bf16x8*)&At[rb*16 + lr][kk*32 + lk*8];
        #pragma unroll
        for (int j = 0; j < 12; ++j) {
            int col = jh*192 + j*16 + lr;
            bf16x8 b = *(const bf16x8*)&w1t[col * DIM + kk*32 + lk*8];
            acc[j] = __builtin_amdgcn_mfma_f32_16x16x32_bf16(a, b, acc[j], 0, 0, 0);
        }
    }

    // ---- bias + exact GELU -> Ht ----
    #pragma unroll
    for (int j = 0; j < 12; ++j) {
        int col = jh*192 + j*16 + lr;
        float bb = b1[col];
        #pragma unroll
        for (int r = 0; r < 4; ++r) {
            float vv = acc[j][r] + bb;
            float ge = 0.5f * vv * (1.f + erff(vv * 0.70710678f));
            Ht[rb*16 + lk*4 + r][col] = __float2bfloat16(ge);
        }
    }
    __syncthreads();

    // ---- GEMM2: [32,384] @ [384,96]; wave (rb,jh) does 16 rows x 48 cols ----
    f32x4 acc2[3];
    #pragma unroll
    for (int j = 0; j < 3; ++j) acc2[j] = (f32x4){0.f, 0.f, 0.f, 0.f};

    #pragma unroll
    for (int kk = 0; kk < 12; ++kk) {
        bf16x8 a = *(const bf16x8*)&Ht[rb*16 + lr][kk*32 + lk*8];
        #pragma unroll
        for (int j = 0; j < 3; ++j) {
            int col = jh*48 + j*16 + lr;
            bf16x8 b = *(const bf16x8*)&w2t[col * HID + kk*32 + lk*8];
            acc2[j] = __builtin_amdgcn_mfma_f32_16x16x32_bf16(a, b, acc2[j], 0, 0, 0);
        }
    }

    // ---- epilogue: + b2 + residual (bf16 feats), NT store ----
    #pragma unroll
    for (int j = 0; j < 3; ++j) {
        int col = jh*48 + j*16 + lr;
        float bb = b2[col];
        #pragma unroll
        for (int r = 0; r < 4; ++r) {
            int grow = blk * TM + rb*16 + lk*4 + r;
            int off = grow * DIM + col;
            float res = (float)featsb[off];
            __builtin_nontemporal_store(acc2[j][r] + bb + res, &out[off]);
        }
    }
}

extern "C" void kernel_launch(void* const* d_in, const int* in_sizes, int n_in,
                              void* d_out, int out_size, void* d_ws, size_t ws_size,
                              hipStream_t stream) {
    const float* feats = (const float*)d_in[0];
    const float* w_dw  = (const float*)d_in[1];
    const float* b_dw  = (const float*)d_in[2];
    const float* ln_w  = (const float*)d_in[3];
    const float* ln_b  = (const float*)d_in[4];
    const float* w1    = (const float*)d_in[5];
    const float* b1    = (const float*)d_in[6];
    const float* w2    = (const float*)d_in[7];
    const float* b2    = (const float*)d_in[8];
    const int* in_idx  = (const int*)d_in[9];
    const int* out_idx = (const int*)d_in[10];
    const int* k_idx   = (const int*)d_in[11];
    float* out = (float*)d_out;

    char* ws = (char*)d_ws;
    unsigned* slots = (unsigned*)ws;                               // 51,200,000
    int* cnt   = (int*)(ws + 51200000);                            //    800,000
    __hip_bfloat16* w1t = (__hip_bfloat16*)(ws + 52000000);        //     73,728
    __hip_bfloat16* w2t = (__hip_bfloat16*)(ws + 52073728);        //     73,728
    __bf16* wdwb = (__bf16*)(ws + 52147456);                       //     65,856
    __bf16* featsb = (__bf16*)(ws + 52213312);                     // 38,400,000

    prep<<<(NVOX * DIM / 4) / 256, 256, 0, stream>>>(feats, w1, w2, w_dw,
                                                     featsb, w1t, w2t, wdwb, cnt);
    scatter_slots<<<NEDGE / 4 / 256, 256, 0, stream>>>((const int4*)in_idx,
                                                       (const int4*)out_idx,
                                                       (const int4*)k_idx, cnt, slots);
    fused_all<<<NVOX / TM, 256, 0, stream>>>(featsb, wdwb, b_dw, ln_w, ln_b,
                                             w1t, b1, w2t, b2, slots, cnt, out);
}